// Round 6
// baseline (28.245 us; speedup 1.0000x reference)
//
#include <hip/hip_runtime.h>
#include <math.h>

#define NPIX (8 * 256 * 256)   // B*H*W
#define CC 16                  // C
#define KK 8                   // K classes
#define TPB 256                // 4 waves
#define NTILES 8               // 16-px tiles per wave -> 512 px/block
#define GRID (NPIX / 512)      // 1024 blocks = 4 blocks/CU

typedef __attribute__((ext_vector_type(8))) short short8;  // 8 bf16 (4 VGPRs)
typedef __attribute__((ext_vector_type(4))) float f32x4;

#if __has_builtin(__builtin_amdgcn_exp2f)
#define EXP2F(v) __builtin_amdgcn_exp2f(v)
#else
#define EXP2F(v) exp2f(v)
#endif

// Fragment tables built by prep_kernel:
//   g_a1[k*64+l] : A1 = [W_hi, W_hi]   (bf16 pairs, 4 dwords)
//   g_a2[k*64+l] : A2 = [W_lo, biasslot]  (bias_hi/lo in g==0,f<2 odd slots)
//   g_c0[k]      : (-8*ln(2pi) - logdet_k) * log2(e)
// prob_k = exp2(c0_k - sum_i z_i^2), z = SC*Linv*x - SC*Linv*mean,
// computed as MFMA(A1,[x_hi,x_lo]) + MFMA(A2,[x_hi,1.0]).
__device__ int4  g_a1[KK * 64];
__device__ int4  g_a2[KK * 64];
__device__ float g_c0[KK];

__global__ void prep_kernel(const float* __restrict__ st,
                            const float* __restrict__ mean) {
    __shared__ float linv[KK][CC][CC + 1];   // unscaled tril inverse
    __shared__ float bias[KK][CC];           // -SC*(Linv*mean)
    const int t = threadIdx.x;               // 128 threads
    const int k = t >> 4, j = t & 15;
    const float* L = st + k * CC * CC;

    // column j of inv(tril(L))
    float col[CC];
#pragma unroll
    for (int i = 0; i < CC; ++i) {
        float s = (i == j) ? 1.0f : 0.0f;
#pragma unroll
        for (int m = 0; m < i; ++m) s = fmaf(-L[i * CC + m], col[m], s);
        col[i] = (i < j) ? 0.0f : s / L[i * CC + i];
        linv[k][i][j] = col[i];
    }
    if (t < KK) {
        const float* Lk = st + t * CC * CC;
        float ld = 0.0f;
#pragma unroll
        for (int i = 0; i < CC; ++i) ld += __logf(fabsf(Lk[i * CC + i]));
        g_c0[t] = (-14.70301653f - ld) * 1.44269504f;  // -0.5*16*ln(2pi), log2(e)
    }
    __syncthreads();

    const float SCALE = 0.8493218891f;       // sqrt(0.5*log2(e))
    {   // thread (k, i=j): bias row
        float b = 0.0f;
#pragma unroll
        for (int j2 = 0; j2 < CC; ++j2) b = fmaf(linv[k][j][j2], mean[k * CC + j2], b);
        bias[k][j] = -b * SCALE;
    }
    __syncthreads();

    // pack fragments: 512 (k,lane) slots, 4 per thread
#pragma unroll
    for (int q = 0; q < 4; ++q) {
        const int idx = (t << 2) | q;
        const int kk2 = idx >> 6, l = idx & 63;
        const int i = l & 15, g = l >> 4;
        int a1d[4], a2d[4];
#pragma unroll
        for (int f = 0; f < 4; ++f) {
            const float w = SCALE * linv[kk2][i][4 * g + f];
            const unsigned wb = __float_as_uint(w) & 0xFFFF0000u;
            const unsigned hb = wb >> 16;
            a1d[f] = (int)(hb | (hb << 16));                       // [W_hi, W_hi]
            const float wl = w - __uint_as_float(wb);
            unsigned odd = 0u;
            if (g == 0 && f < 2) {                                 // bias hi/lo slots
                const float b = bias[kk2][i];
                const unsigned bb = __float_as_uint(b) & 0xFFFF0000u;
                if (f == 0) odd = bb >> 16;
                else        odd = __float_as_uint(b - __uint_as_float(bb)) >> 16;
            }
            a2d[f] = (int)((__float_as_uint(wl) >> 16) | (odd << 16));  // [W_lo, bias]
        }
        g_a1[idx] = make_int4(a1d[0], a1d[1], a1d[2], a1d[3]);
        g_a2[idx] = make_int4(a2d[0], a2d[1], a2d[2], a2d[3]);
    }
}

__global__ __launch_bounds__(TPB, 4) void fuzzy_kernel(const float* __restrict__ x,
                                                       float* __restrict__ out) {
    const int t = threadIdx.x, lane = t & 63, wid = t >> 6;

    short8 A1[KK], A2[KK];
    float c0v[KK];
#pragma unroll
    for (int k = 0; k < KK; ++k) {
        A1[k]  = __builtin_bit_cast(short8, g_a1[k * 64 + lane]);
        A2[k]  = __builtin_bit_cast(short8, g_a2[k * 64 + lane]);
        c0v[k] = g_c0[k];                    // wave-uniform -> SGPR
    }

    const int p = lane & 15, g = lane >> 4;
    const size_t wbase = (size_t)blockIdx.x * 512 + (size_t)wid * 128;
    const float* xptr = x + wbase * CC + (size_t)(p * 16 + g * 4);
    float* optr = out + (wbase + p) * 24 + g * 4;

    float4 xf0 = *(const float4*)(xptr);

#pragma unroll
    for (int tt = 0; tt < NTILES; ++tt) {
        const float4 xf1 = (tt + 1 < NTILES) ? *(const float4*)(xptr + (size_t)(tt + 1) * 256) : xf0;

        float* o = optr + (size_t)tt * 384;   // 16 px * 24 floats
        *(float4*)o = xf0;                    // passthrough: independent, store early

        // pack B1 = [x_hi, x_lo], B2 = [x_hi, 1.0]
        int b1[4], b2[4];
        {
            const float xs[4] = {xf0.x, xf0.y, xf0.z, xf0.w};
#pragma unroll
            for (int f = 0; f < 4; ++f) {
                const unsigned th = __float_as_uint(xs[f]) & 0xFFFF0000u;
                const float lo = xs[f] - __uint_as_float(th);
                b1[f] = (int)((th >> 16) | (__float_as_uint(lo) & 0xFFFF0000u));
                b2[f] = (int)((th >> 16) | 0x3F800000u);
            }
        }
        const short8 B1 = __builtin_bit_cast(short8, make_int4(b1[0], b1[1], b1[2], b1[3]));
        const short8 B2 = __builtin_bit_cast(short8, make_int4(b2[0], b2[1], b2[2], b2[3]));

        f32x4 acc[KK];
#pragma unroll
        for (int k = 0; k < KK; ++k) acc[k] = (f32x4){0.0f, 0.0f, 0.0f, 0.0f};
#pragma unroll
        for (int k = 0; k < KK; ++k)
            acc[k] = __builtin_amdgcn_mfma_f32_16x16x32_bf16(A1[k], B1, acc[k], 0, 0, 0);
#pragma unroll
        for (int k = 0; k < KK; ++k)
            acc[k] = __builtin_amdgcn_mfma_f32_16x16x32_bf16(A2[k], B2, acc[k], 0, 0, 0);

        // quad = sum_i z^2 : squares + VALU permlane folds (no LDS pipe)
        float pr[KK];
#pragma unroll
        for (int k = 0; k < KK; ++k) {
            float s = acc[k][0] * acc[k][0];
            s = fmaf(acc[k][1], acc[k][1], s);
            s = fmaf(acc[k][2], acc[k][2], s);
            s = fmaf(acc[k][3], acc[k][3], s);
#if __has_builtin(__builtin_amdgcn_permlane16_swap)
            {
                auto r = __builtin_amdgcn_permlane16_swap(__float_as_uint(s), __float_as_uint(s), false, false);
                s = __uint_as_float(r[0]) + __uint_as_float(r[1]);
                auto r2 = __builtin_amdgcn_permlane32_swap(__float_as_uint(s), __float_as_uint(s), false, false);
                s = __uint_as_float(r2[0]) + __uint_as_float(r2[1]);
            }
#else
            s += __shfl_xor(s, 16, 64);
            s += __shfl_xor(s, 32, 64);
#endif
            pr[k] = EXP2F(c0v[k] - s);
        }
        // tree-shaped sum of squares (depth 3)
        const float s01 = fmaf(pr[1], pr[1], pr[0] * pr[0]);
        const float s23 = fmaf(pr[3], pr[3], pr[2] * pr[2]);
        const float s45 = fmaf(pr[5], pr[5], pr[4] * pr[4]);
        const float s67 = fmaf(pr[7], pr[7], pr[6] * pr[6]);
        const float ss = (s01 + s23) + (s45 + s67);
        const float inv = rsqrtf(fmaxf(ss, 1e-12f));

        if (lane < 32) {                      // g==0 -> cols 16..19, g==1 -> cols 20..23
            float4 pv;
            if (g == 0) pv = make_float4(pr[0] * inv, pr[1] * inv, pr[2] * inv, pr[3] * inv);
            else        pv = make_float4(pr[4] * inv, pr[5] * inv, pr[6] * inv, pr[7] * inv);
            *(float4*)(o + 16) = pv;
        }

        xf0 = xf1;
    }
}

extern "C" void kernel_launch(void* const* d_in, const int* in_sizes, int n_in,
                              void* d_out, int out_size, void* d_ws, size_t ws_size,
                              hipStream_t stream) {
    const float* x    = (const float*)d_in[0];   // [B,H,W,C] fp32
    const float* mean = (const float*)d_in[1];   // [K,C] fp32
    const float* st   = (const float*)d_in[2];   // [K,C,C] fp32
    float* out = (float*)d_out;                  // [B,H,W,C+K] fp32

    prep_kernel<<<1, 128, 0, stream>>>(st, mean);
    fuzzy_kernel<<<GRID, TPB, 0, stream>>>(x, out);
}